// Round 1
// baseline (90432.361 us; speedup 1.0000x reference)
//
#include <hip/hip_runtime.h>
#include <hip/hip_cooperative_groups.h>
#include <cstdint>
#include <cstddef>

#define B_ 32
#define L_ 1024
#define I_ 1024
#define H_ 1024
#define G3_ 3072

namespace cg = cooperative_groups;

typedef short short8 __attribute__((ext_vector_type(8)));
typedef float floatx4 __attribute__((ext_vector_type(4)));

__device__ __forceinline__ unsigned short f2bf_rne(float f) {
    unsigned u = __float_as_uint(f);
    unsigned r = (u + 0x7fffu + ((u >> 16) & 1u)) >> 16;
    return (unsigned short)r;
}
__device__ __forceinline__ float bf2f(unsigned short u) {
    return __uint_as_float(((unsigned)u) << 16);
}

// ---- prep: split x into bf16 hi/lo -----------------------------------------
__global__ void k_split_x(const float* __restrict__ src,
                          unsigned short* __restrict__ hi,
                          unsigned short* __restrict__ lo, int n) {
    int i = blockIdx.x * blockDim.x + threadIdx.x;
    int stride = gridDim.x * blockDim.x;
    for (; i < n; i += stride) {
        float f = src[i];
        unsigned short hb = f2bf_rne(f);
        hi[i] = hb;
        lo[i] = f2bf_rne(f - bf2f(hb));
    }
}

// ---- prep: transpose weights [K][3H] -> [col][K], split bf16 hi/lo ---------
// wt layout: mat in {Wi0,Wh0,Wi1,Wh1}: base = mat*2*G3*K ; hi then lo (G3*K each)
__global__ __launch_bounds__(256) void k_trans_w(const float* __restrict__ Wi,
                                                 const float* __restrict__ Wh,
                                                 unsigned short* __restrict__ wt) {
    int mat = blockIdx.y;            // 0=Wi0 1=Wh0 2=Wi1 3=Wh1
    int layer = mat >> 1, ish = mat & 1;
    const float* src = (ish ? Wh : Wi) + (size_t)layer * I_ * G3_;
    unsigned short* dhi = wt + (size_t)mat * 2u * ((size_t)G3_ * I_);
    unsigned short* dlo = dhi + (size_t)G3_ * I_;
    int kt = blockIdx.x & 15;        // 16 k-tiles of 64
    int ct = blockIdx.x >> 4;        // 48 col-tiles of 64
    __shared__ float tile[64][65];
    int tid = threadIdx.x;
    int c_in = tid & 63, kr = tid >> 6;
    for (int pass = 0; pass < 16; ++pass) {
        int k = kt * 64 + pass * 4 + kr;
        tile[pass * 4 + kr][c_in] = src[(size_t)k * G3_ + ct * 64 + c_in];
    }
    __syncthreads();
    int k_out = tid & 63, cr = tid >> 6;
    for (int pass = 0; pass < 16; ++pass) {
        int c = ct * 64 + pass * 4 + cr;
        float f = tile[k_out][pass * 4 + cr];
        unsigned short hb = f2bf_rne(f);
        size_t o = (size_t)c * I_ + kt * 64 + k_out;
        dhi[o] = hb;
        dlo[o] = f2bf_rne(f - bf2f(hb));
    }
}

// ---- persistent GRU kernel --------------------------------------------------
// 256 blocks = 4 types x 64 col-groups. Types:
//   0: gi0[s]   = x[s] @ Wi0            (writes gib buf0 slot s&1)
//   1: h0[s-1]  = act(gi0[s-1], h0[s-2]@Wh0)   (writes h0 slot (s-1)&1)
//   2: gi1[s-2] = h0[s-2] @ Wi1         (writes gib buf1 slot s&1)
//   3: h1[s-3]  = act(gi1[s-3], h1[s-4]@Wh1) + out[t=s-3]
// One grid.sync per step; all reads are of data written in previous steps.
// Weights for a block's 16 columns live entirely in VGPRs (96/lane).
// hst: 4 bufs {h0h,h0l,h1h,h1l} x 2 slots x 32768 bf16
// gib: 2 bufs {gi0,gi1} x 2 slots x (32*3072) f32
__global__ __launch_bounds__(512, 2) void k_gru(
    const unsigned short* __restrict__ xh, const unsigned short* __restrict__ xl,
    const unsigned short* __restrict__ wt,
    const float* __restrict__ b_i, const float* __restrict__ b_h,
    unsigned short* __restrict__ hst, float* __restrict__ gib,
    float* __restrict__ out) {

    const int blk = blockIdx.x;
    const int type = blk >> 6;       // 0:Wi0 1:Wh0+act0 2:Wi1 3:Wh1+act1
    const int grp = blk & 63;
    const int layer = type >> 1;
    const bool is_h = (type & 1) != 0;
    const int tid = threadIdx.x, wave = tid >> 6, lane = tid & 63;
    const int arow = lane & 15;
    const int klane = (lane >> 4) * 8;
    const int k0 = wave * 128 + klane;   // 8 waves split k 8-ways
    const int cb = grp * 16 + (lane & 15);

    // --- load this block's weight slice into registers (held whole sequence) -
    const unsigned short* bHbase = wt + (size_t)type * 2u * ((size_t)G3_ * I_);
    const unsigned short* bLbase = bHbase + (size_t)G3_ * I_;
    short8 w[4][3][2];
#pragma unroll
    for (int ks = 0; ks < 4; ++ks)
#pragma unroll
        for (int n = 0; n < 3; ++n) {
            size_t bo = (size_t)(n * H_ + cb) * I_ + (size_t)(k0 + ks * 32);
            w[ks][n][0] = *(const short8*)(bHbase + bo);
            w[ks][n][1] = *(const short8*)(bLbase + bo);
        }
    asm volatile("" ::: "memory");   // keep weight loads hoisted out of the loop

    // activation-phase thread mapping: one (b,u) pair per thread
    const int b_act = tid >> 4, uu = tid & 15;
    const int u = grp * 16 + uu;
    float bir = 0.f, biz = 0.f, bin = 0.f, bhr = 0.f, bhz = 0.f, bhn = 0.f;
    if (is_h) {
        const float* bi = b_i + (size_t)layer * G3_;
        const float* bh = b_h + (size_t)layer * G3_;
        bir = bi[u]; biz = bi[H_ + u]; bin = bi[2 * H_ + u];
        bhr = bh[u]; bhz = bh[H_ + u]; bhn = bh[2 * H_ + u];
    }
    float hp = 0.f;                  // f32 h_prev for this thread's (b,u)

    __shared__ float red[8][32][50]; // pad 50: 4-row groups land on distinct banks
    cg::grid_group grid = cg::this_grid();

    for (int s = 0; s <= L_ + 2; ++s) {
        const int rd = s & 1, wr = rd ^ 1;
        bool act;
        const unsigned short *aH = nullptr, *aL = nullptr;
        size_t astr;
        if (type == 0) {
            act = (s < L_);
            size_t base = ((size_t)arow * L_ + s) * I_;
            aH = xh + base; aL = xl + base;
            astr = (size_t)16 * L_ * I_;
        } else {
            astr = (size_t)16 * I_;
            int hb;
            if (type == 1)      { act = (s >= 1 && s <= L_);     hb = 0; }
            else if (type == 2) { act = (s >= 2 && s <= L_ + 1); hb = 0; }
            else                { act = (s >= 3);                hb = 1; }
            aH = hst + ((size_t)(hb * 2 + 0) * 2 + rd) * 32768 + (size_t)arow * I_;
            aL = hst + ((size_t)(hb * 2 + 1) * 2 + rd) * 32768 + (size_t)arow * I_;
        }

        // prefetch gi partials (written last step by the paired gi-block)
        float gir = 0.f, giz = 0.f, gin = 0.f;
        if (is_h && act) {
            const float* gsrc = gib + ((size_t)layer * 2 + wr) * ((size_t)B_ * G3_)
                                    + (size_t)b_act * G3_;
            gir = gsrc[u]; giz = gsrc[H_ + u]; gin = gsrc[2 * H_ + u];
        }

        if (act) {
            floatx4 acc[2][3] = {};
#pragma unroll
            for (int ks = 0; ks < 4; ++ks) {
                const int kk = k0 + ks * 32;
                short8 a0h_ = *(const short8*)(aH + kk);
                short8 a0l_ = *(const short8*)(aL + kk);
                short8 a1h_ = *(const short8*)(aH + astr + kk);
                short8 a1l_ = *(const short8*)(aL + astr + kk);
#pragma unroll
                for (int n = 0; n < 3; ++n) {
                    acc[0][n] = __builtin_amdgcn_mfma_f32_16x16x32_bf16(a0h_, w[ks][n][0], acc[0][n], 0, 0, 0);
                    acc[0][n] = __builtin_amdgcn_mfma_f32_16x16x32_bf16(a0h_, w[ks][n][1], acc[0][n], 0, 0, 0);
                    acc[0][n] = __builtin_amdgcn_mfma_f32_16x16x32_bf16(a0l_, w[ks][n][0], acc[0][n], 0, 0, 0);
                    acc[1][n] = __builtin_amdgcn_mfma_f32_16x16x32_bf16(a1h_, w[ks][n][0], acc[1][n], 0, 0, 0);
                    acc[1][n] = __builtin_amdgcn_mfma_f32_16x16x32_bf16(a1h_, w[ks][n][1], acc[1][n], 0, 0, 0);
                    acc[1][n] = __builtin_amdgcn_mfma_f32_16x16x32_bf16(a1l_, w[ks][n][0], acc[1][n], 0, 0, 0);
                }
            }
#pragma unroll
            for (int m = 0; m < 2; ++m)
#pragma unroll
                for (int n = 0; n < 3; ++n)
#pragma unroll
                    for (int r = 0; r < 4; ++r)
                        red[wave][16 * m + (lane >> 4) * 4 + r][16 * n + (lane & 15)] = acc[m][n][r];
        }
        __syncthreads();

        if (act) {
            float sr = 0.f, sz = 0.f, sn = 0.f;
#pragma unroll
            for (int wv = 0; wv < 8; ++wv) {
                sr += red[wv][b_act][uu];
                sz += red[wv][b_act][16 + uu];
                sn += red[wv][b_act][32 + uu];
            }
            if (!is_h) {
                // gi producer: publish partial pre-activations
                float* gdst = gib + ((size_t)layer * 2 + rd) * ((size_t)B_ * G3_)
                                  + (size_t)b_act * G3_;
                gdst[u] = sr; gdst[H_ + u] = sz; gdst[2 * H_ + u] = sn;
            } else {
                float vr = gir + bir + sr + bhr;
                float vz = giz + biz + sz + bhz;
                float r = 1.f / (1.f + __expf(-vr));
                float z = 1.f / (1.f + __expf(-vz));
                float ht = tanhf(gin + bin + r * (sn + bhn));
                float hn = z * hp + (1.f - z) * ht;
                hp = hn;
                unsigned short hb16 = f2bf_rne(hn);
                unsigned short* hh = hst + ((size_t)(layer * 2 + 0) * 2 + wr) * 32768;
                unsigned short* hl = hst + ((size_t)(layer * 2 + 1) * 2 + wr) * 32768;
                hh[b_act * H_ + u] = hb16;
                hl[b_act * H_ + u] = f2bf_rne(hn - bf2f(hb16));
                if (type == 3) {
                    int t = s - 3;
                    out[((size_t)b_act * L_ + t) * H_ + u] = hn;
                    if (t == L_ - 1)
                        out[(size_t)B_ * L_ * H_ + (size_t)B_ * H_ + b_act * H_ + u] = hn;
                } else {
                    if (s == L_)  // h0[L-1] final state
                        out[(size_t)B_ * L_ * H_ + b_act * H_ + u] = hn;
                }
            }
        }
        __threadfence();
        grid.sync();
    }
}

extern "C" void kernel_launch(void* const* d_in, const int* in_sizes, int n_in,
                              void* d_out, int out_size, void* d_ws, size_t ws_size,
                              hipStream_t stream) {
    const float* x  = (const float*)d_in[0];
    const float* Wi = (const float*)d_in[1];
    const float* bi = (const float*)d_in[2];
    const float* Wh = (const float*)d_in[3];
    const float* bh = (const float*)d_in[4];
    float* out = (float*)d_out;
    char* ws = (char*)d_ws;

    // ws layout (bytes):
    //  [0, 64MB)        x_hi bf16 [B][L][I]
    //  [64MB, 128MB)    x_lo
    //  [128MB, 176MB)   wt: 4 mats x {hi,lo} x [3072][1024] bf16
    //  [176MB, +512KB)  hst: 4 bufs x 2 slots x 32768 bf16
    //  [+512KB, +2MB)   gib: 2 bufs x 2 slots x 98304 f32
    unsigned short* xh  = (unsigned short*)(ws);
    unsigned short* xl  = (unsigned short*)(ws + 67108864);
    unsigned short* wt  = (unsigned short*)(ws + 134217728);
    unsigned short* hst = (unsigned short*)(ws + 184549376);
    float*          gib = (float*)(ws + 184549376 + 524288);

    hipMemsetAsync(ws + 184549376, 0, 524288, stream);
    k_split_x<<<4096, 256, 0, stream>>>(x, xh, xl, B_ * L_ * I_);
    k_trans_w<<<dim3(768, 4), 256, 0, stream>>>(Wi, Wh, wt);

    void* args[] = {&xh, &xl, &wt, &bi, &bh, &hst, &gib, &out};
    hipLaunchCooperativeKernel((void*)k_gru, dim3(256), dim3(512), args, 0, stream);
}

// Round 2
// 22747.206 us; speedup vs baseline: 3.9755x; 3.9755x over previous
//
#include <hip/hip_runtime.h>
#include <cstdint>
#include <cstddef>

#define B_ 32
#define L_ 1024
#define I_ 1024
#define H_ 1024
#define G3_ 3072
#define G3I ((size_t)G3_ * I_)

typedef short short8 __attribute__((ext_vector_type(8)));
typedef float floatx4 __attribute__((ext_vector_type(4)));

__device__ __forceinline__ unsigned short f2bf_rne(float f) {
    unsigned u = __float_as_uint(f);
    unsigned r = (u + 0x7fffu + ((u >> 16) & 1u)) >> 16;
    return (unsigned short)r;
}
__device__ __forceinline__ float bf2f(unsigned short u) {
    return __uint_as_float(((unsigned)u) << 16);
}

// ---- prep: transpose weights [K][3H] -> [col][K], split bf16 hi/lo ---------
// wt layout: mat in {Wi0,Wh0,Wi1,Wh1}: base = mat*2*G3I ; hi then lo (G3I each)
__global__ __launch_bounds__(256) void k_trans_w(const float* __restrict__ Wi,
                                                 const float* __restrict__ Wh,
                                                 unsigned short* __restrict__ wt) {
    int mat = blockIdx.y;            // 0=Wi0 1=Wh0 2=Wi1 3=Wh1
    int layer = mat >> 1, ish = mat & 1;
    const float* src = (ish ? Wh : Wi) + (size_t)layer * I_ * G3_;
    unsigned short* dhi = wt + (size_t)mat * 2u * G3I;
    unsigned short* dlo = dhi + G3I;
    int kt = blockIdx.x & 15;        // 16 k-tiles of 64
    int ct = blockIdx.x >> 4;        // 48 col-tiles of 64
    __shared__ float tile[64][65];
    int tid = threadIdx.x;
    int c_in = tid & 63, kr = tid >> 6;
    for (int pass = 0; pass < 16; ++pass) {
        int k = kt * 64 + pass * 4 + kr;
        tile[pass * 4 + kr][c_in] = src[(size_t)k * G3_ + ct * 64 + c_in];
    }
    __syncthreads();
    int k_out = tid & 63, cr = tid >> 6;
    for (int pass = 0; pass < 16; ++pass) {
        int c = ct * 64 + pass * 4 + cr;
        float f = tile[k_out][pass * 4 + cr];
        unsigned short hb = f2bf_rne(f);
        size_t o = (size_t)c * I_ + kt * 64 + k_out;
        dhi[o] = hb;
        dlo[o] = f2bf_rne(f - bf2f(hb));
    }
}

// ---- precompute gi0 = x @ Wi0 for ALL timesteps (one big GEMM) -------------
// x is f32 [B][L][I] (row r = b*L+t); output gi0 f32 [t][b][3H].
// Block: 512 thr (8 waves), tile M=64 (4 m-subtiles) x N=64 (4 n-subtiles);
// wave w -> (mq = w&3, n-pair = (w>>2)*2 + {0,1}), full k=1024 per wave.
__global__ __launch_bounds__(512) void k_gi0(const float* __restrict__ xf,
                                             const unsigned short* __restrict__ wt,
                                             float* __restrict__ gi0) {
    int mt = blockIdx.x;             // 512 m-tiles of 64 rows
    int nt = blockIdx.y;             // 48 n-tiles of 64 cols
    int tid = threadIdx.x, wave = tid >> 6, lane = tid & 63;
    int mq = wave & 3, npair = wave >> 2;
    int arow = lane & 15, klq = (lane >> 4) * 8;
    const unsigned short* wHi = wt;  // Wi0 hi
    const unsigned short* wLo = wt + G3I;
    size_t abase = ((size_t)(mt * 64 + mq * 16 + arow)) * I_;
    int c0 = nt * 64 + npair * 32 + (lane & 15);
    floatx4 acc[2] = {};
    for (int it = 0; it < 32; ++it) {
        int kk = it * 32 + klq;
        float4 f0 = *(const float4*)(xf + abase + kk);
        float4 f1 = *(const float4*)(xf + abase + kk + 4);
        short8 ah, al;
        {
            float v0 = f0.x, v1 = f0.y, v2 = f0.z, v3 = f0.w;
            float v4 = f1.x, v5 = f1.y, v6 = f1.z, v7 = f1.w;
            unsigned short hb;
            hb = f2bf_rne(v0); ah[0] = (short)hb; al[0] = (short)f2bf_rne(v0 - bf2f(hb));
            hb = f2bf_rne(v1); ah[1] = (short)hb; al[1] = (short)f2bf_rne(v1 - bf2f(hb));
            hb = f2bf_rne(v2); ah[2] = (short)hb; al[2] = (short)f2bf_rne(v2 - bf2f(hb));
            hb = f2bf_rne(v3); ah[3] = (short)hb; al[3] = (short)f2bf_rne(v3 - bf2f(hb));
            hb = f2bf_rne(v4); ah[4] = (short)hb; al[4] = (short)f2bf_rne(v4 - bf2f(hb));
            hb = f2bf_rne(v5); ah[5] = (short)hb; al[5] = (short)f2bf_rne(v5 - bf2f(hb));
            hb = f2bf_rne(v6); ah[6] = (short)hb; al[6] = (short)f2bf_rne(v6 - bf2f(hb));
            hb = f2bf_rne(v7); ah[7] = (short)hb; al[7] = (short)f2bf_rne(v7 - bf2f(hb));
        }
#pragma unroll
        for (int n = 0; n < 2; ++n) {
            size_t bo = (size_t)(c0 + n * 16) * I_ + kk;
            short8 bh_ = *(const short8*)(wHi + bo);
            short8 bl_ = *(const short8*)(wLo + bo);
            acc[n] = __builtin_amdgcn_mfma_f32_16x16x32_bf16(ah, bh_, acc[n], 0, 0, 0);
            acc[n] = __builtin_amdgcn_mfma_f32_16x16x32_bf16(ah, bl_, acc[n], 0, 0, 0);
            acc[n] = __builtin_amdgcn_mfma_f32_16x16x32_bf16(al, bh_, acc[n], 0, 0, 0);
        }
    }
#pragma unroll
    for (int n = 0; n < 2; ++n)
#pragma unroll
        for (int r = 0; r < 4; ++r) {
            int rr = mt * 64 + mq * 16 + (lane >> 4) * 4 + r;
            int b = rr >> 10, t = rr & 1023;
            gi0[((size_t)t * B_ + b) * G3_ + c0 + n * 16] = acc[n][r];
        }
}

// ---- per-superstep kernel ---------------------------------------------------
// 256 blocks x 512 thr. Block `grp` owns hidden units [grp*4, grp*4+4) and
// computes gh0 = h0[s-1]@Wh0, gi1 = h0[s-1]@Wi1, gh1 = h1[s-2]@Wh1 for those
// units (12 real MFMA cols = 3 gates x 4 units; lanes 12-15 duplicate gate 2).
// act0 (tid<128)  : h0[s]   = GRU(gi0[s] precomputed, gh0)
// act1 (tid<256)  : h1[s-1] = GRU(gi1,                gh1)  + out row t=s-1
// hst: {h0h,h0l,h1h,h1l} x 2 slots x 32768 bf16 ; hsf: {h0,h1} x 2 slots f32.
__global__ __launch_bounds__(512) void k_step2(
    int s,
    const unsigned short* __restrict__ wt,
    const float* __restrict__ gi0,
    const float* __restrict__ b_i, const float* __restrict__ b_h,
    unsigned short* __restrict__ hst, float* __restrict__ hsf,
    float* __restrict__ out) {

    const int grp = blockIdx.x;
    const int tid = threadIdx.x, wave = tid >> 6, lane = tid & 63;
    const int arow = lane & 15, klq = (lane >> 4) * 8;
    const int c = lane & 15;
    const int gc = (c >> 2) < 3 ? (c >> 2) : 2;
    const size_t wo = ((size_t)(gc * H_ + grp * 4 + (c & 3))) * I_;

    const int rd0 = (s - 1) & 1;     // slot of h0[s-1]
    const int rd1 = s & 1;           // slot of h1[s-2]
    const unsigned short* a0h = hst + (size_t)(0 + rd0) * 32768;
    const unsigned short* a0l = hst + (size_t)(2 + rd0) * 32768;
    const unsigned short* a1h = hst + (size_t)(4 + rd1) * 32768;
    const unsigned short* a1l = hst + (size_t)(6 + rd1) * 32768;
    const unsigned short* w1h = wt + 1 * 2 * G3I; const unsigned short* w1l = w1h + G3I;
    const unsigned short* w2h = wt + 2 * 2 * G3I; const unsigned short* w2l = w2h + G3I;
    const unsigned short* w3h = wt + 3 * 2 * G3I; const unsigned short* w3l = w3h + G3I;

    floatx4 acc[3][2] = {};
#pragma unroll
    for (int ks = 0; ks < 4; ++ks) {
        const int kk = wave * 128 + klq + ks * 32;
        short8 p0h = *(const short8*)(a0h + (size_t)arow * I_ + kk);
        short8 p0l = *(const short8*)(a0l + (size_t)arow * I_ + kk);
        short8 p1h = *(const short8*)(a0h + (size_t)(16 + arow) * I_ + kk);
        short8 p1l = *(const short8*)(a0l + (size_t)(16 + arow) * I_ + kk);
        short8 q0h = *(const short8*)(a1h + (size_t)arow * I_ + kk);
        short8 q0l = *(const short8*)(a1l + (size_t)arow * I_ + kk);
        short8 q1h = *(const short8*)(a1h + (size_t)(16 + arow) * I_ + kk);
        short8 q1l = *(const short8*)(a1l + (size_t)(16 + arow) * I_ + kk);
        short8 u1h = *(const short8*)(w1h + wo + kk);
        short8 u1l = *(const short8*)(w1l + wo + kk);
        short8 u2h = *(const short8*)(w2h + wo + kk);
        short8 u2l = *(const short8*)(w2l + wo + kk);
        short8 u3h = *(const short8*)(w3h + wo + kk);
        short8 u3l = *(const short8*)(w3l + wo + kk);
        acc[0][0] = __builtin_amdgcn_mfma_f32_16x16x32_bf16(p0h, u1h, acc[0][0], 0, 0, 0);
        acc[0][0] = __builtin_amdgcn_mfma_f32_16x16x32_bf16(p0h, u1l, acc[0][0], 0, 0, 0);
        acc[0][0] = __builtin_amdgcn_mfma_f32_16x16x32_bf16(p0l, u1h, acc[0][0], 0, 0, 0);
        acc[0][1] = __builtin_amdgcn_mfma_f32_16x16x32_bf16(p1h, u1h, acc[0][1], 0, 0, 0);
        acc[0][1] = __builtin_amdgcn_mfma_f32_16x16x32_bf16(p1h, u1l, acc[0][1], 0, 0, 0);
        acc[0][1] = __builtin_amdgcn_mfma_f32_16x16x32_bf16(p1l, u1h, acc[0][1], 0, 0, 0);
        acc[1][0] = __builtin_amdgcn_mfma_f32_16x16x32_bf16(p0h, u2h, acc[1][0], 0, 0, 0);
        acc[1][0] = __builtin_amdgcn_mfma_f32_16x16x32_bf16(p0h, u2l, acc[1][0], 0, 0, 0);
        acc[1][0] = __builtin_amdgcn_mfma_f32_16x16x32_bf16(p0l, u2h, acc[1][0], 0, 0, 0);
        acc[1][1] = __builtin_amdgcn_mfma_f32_16x16x32_bf16(p1h, u2h, acc[1][1], 0, 0, 0);
        acc[1][1] = __builtin_amdgcn_mfma_f32_16x16x32_bf16(p1h, u2l, acc[1][1], 0, 0, 0);
        acc[1][1] = __builtin_amdgcn_mfma_f32_16x16x32_bf16(p1l, u2h, acc[1][1], 0, 0, 0);
        acc[2][0] = __builtin_amdgcn_mfma_f32_16x16x32_bf16(q0h, u3h, acc[2][0], 0, 0, 0);
        acc[2][0] = __builtin_amdgcn_mfma_f32_16x16x32_bf16(q0h, u3l, acc[2][0], 0, 0, 0);
        acc[2][0] = __builtin_amdgcn_mfma_f32_16x16x32_bf16(q0l, u3h, acc[2][0], 0, 0, 0);
        acc[2][1] = __builtin_amdgcn_mfma_f32_16x16x32_bf16(q1h, u3h, acc[2][1], 0, 0, 0);
        acc[2][1] = __builtin_amdgcn_mfma_f32_16x16x32_bf16(q1h, u3l, acc[2][1], 0, 0, 0);
        acc[2][1] = __builtin_amdgcn_mfma_f32_16x16x32_bf16(q1l, u3h, acc[2][1], 0, 0, 0);
    }

    __shared__ float red[3][8][32][17];
#pragma unroll
    for (int m_ = 0; m_ < 3; ++m_)
#pragma unroll
        for (int mm = 0; mm < 2; ++mm)
#pragma unroll
            for (int r = 0; r < 4; ++r)
                red[m_][wave][mm * 16 + (lane >> 4) * 4 + r][c] = acc[m_][mm][r];
    __syncthreads();

    if (tid < 128) {
        if (s < L_) {
            int b = tid >> 2, uu = tid & 3, u = grp * 4 + uu;
            float sr = 0.f, sz = 0.f, sn = 0.f;
#pragma unroll
            for (int w = 0; w < 8; ++w) {
                sr += red[0][w][b][uu];
                sz += red[0][w][b][4 + uu];
                sn += red[0][w][b][8 + uu];
            }
            const float* gsrc = gi0 + ((size_t)s * B_ + b) * G3_;
            float vr = gsrc[u] + b_i[u] + sr + b_h[u];
            float vz = gsrc[H_ + u] + b_i[H_ + u] + sz + b_h[H_ + u];
            float r_ = 1.f / (1.f + __expf(-vr));
            float z_ = 1.f / (1.f + __expf(-vz));
            float ht = tanhf(gsrc[2 * H_ + u] + b_i[2 * H_ + u] + r_ * (sn + b_h[2 * H_ + u]));
            int wr_ = s & 1;
            float hp = hsf[(size_t)(0 + rd0) * 32768 + b * H_ + u];
            float hn = z_ * hp + (1.f - z_) * ht;
            hsf[(size_t)(0 + wr_) * 32768 + b * H_ + u] = hn;
            unsigned short hb16 = f2bf_rne(hn);
            hst[(size_t)(0 + wr_) * 32768 + b * H_ + u] = hb16;
            hst[(size_t)(2 + wr_) * 32768 + b * H_ + u] = f2bf_rne(hn - bf2f(hb16));
            if (s == L_ - 1) out[(size_t)B_ * L_ * H_ + b * H_ + u] = hn;
        }
    } else if (tid < 256) {
        if (s >= 1) {
            int t = s - 1;
            int b = (tid - 128) >> 2, uu = (tid - 128) & 3, u = grp * 4 + uu;
            float gr = 0.f, gz = 0.f, gn = 0.f, hr = 0.f, hz = 0.f, hn_ = 0.f;
#pragma unroll
            for (int w = 0; w < 8; ++w) {
                gr += red[1][w][b][uu];
                gz += red[1][w][b][4 + uu];
                gn += red[1][w][b][8 + uu];
                hr += red[2][w][b][uu];
                hz += red[2][w][b][4 + uu];
                hn_ += red[2][w][b][8 + uu];
            }
            const float* bi1 = b_i + G3_;
            const float* bh1 = b_h + G3_;
            float vr = gr + bi1[u] + hr + bh1[u];
            float vz = gz + bi1[H_ + u] + hz + bh1[H_ + u];
            float r_ = 1.f / (1.f + __expf(-vr));
            float z_ = 1.f / (1.f + __expf(-vz));
            float ht = tanhf(gn + bi1[2 * H_ + u] + r_ * (hn_ + bh1[2 * H_ + u]));
            int wr1 = (s - 1) & 1;
            float hp = hsf[(size_t)(2 + rd1) * 32768 + b * H_ + u];
            float hnv = z_ * hp + (1.f - z_) * ht;
            hsf[(size_t)(2 + wr1) * 32768 + b * H_ + u] = hnv;
            unsigned short hb16 = f2bf_rne(hnv);
            hst[(size_t)(4 + wr1) * 32768 + b * H_ + u] = hb16;
            hst[(size_t)(6 + wr1) * 32768 + b * H_ + u] = f2bf_rne(hnv - bf2f(hb16));
            out[((size_t)b * L_ + t) * H_ + u] = hnv;
            if (t == L_ - 1) out[(size_t)B_ * L_ * H_ + (size_t)B_ * H_ + b * H_ + u] = hnv;
        }
    }
}

extern "C" void kernel_launch(void* const* d_in, const int* in_sizes, int n_in,
                              void* d_out, int out_size, void* d_ws, size_t ws_size,
                              hipStream_t stream) {
    const float* x  = (const float*)d_in[0];
    const float* Wi = (const float*)d_in[1];
    const float* bi = (const float*)d_in[2];
    const float* Wh = (const float*)d_in[3];
    const float* bh = (const float*)d_in[4];
    float* out = (float*)d_out;
    char* ws = (char*)d_ws;

    // ws layout (bytes):
    //  [0, 48MB)              wt: 4 mats x {hi,lo} x [3072][1024] bf16
    //  [50331648, +512KB)     hst: 4 bufs x 2 slots x 32768 bf16
    //  [50855936, +512KB)     hsf: 2 bufs x 2 slots x 32768 f32
    //  [51380224, +384MB)     gi0: f32 [L][B][3H]
    unsigned short* wt  = (unsigned short*)(ws);
    unsigned short* hst = (unsigned short*)(ws + 50331648);
    float*          hsf = (float*)(ws + 50855936);
    float*          gi0 = (float*)(ws + 51380224);

    hipMemsetAsync(ws + 50331648, 0, 1048576, stream);
    k_trans_w<<<dim3(768, 4), 256, 0, stream>>>(Wi, Wh, wt);
    k_gi0<<<dim3(512, 48), 512, 0, stream>>>(x, wt, gi0);
    for (int s = 0; s <= L_; ++s)
        k_step2<<<256, 512, 0, stream>>>(s, wt, gi0, bi, bh, hst, hsf, out);
}